// Round 1
// baseline (36.277 us; speedup 1.0000x reference)
//
#include <hip/hip_runtime.h>

#define N 8192
#define TILE 256
#define NT (N / TILE)   // 32 tiles per dim; 32x32 block grid, upper triangle active

// Stage 1: each block computes partial (sum, count) for one 256x256 pair tile.
__global__ __launch_bounds__(256) void pair_partial(
    const float* __restrict__ pred,
    const float* __restrict__ gt,
    const int* __restrict__ colT,
    const int* __restrict__ colF,
    float* __restrict__ ws_sum,
    unsigned int* __restrict__ ws_cnt)
{
    __shared__ float sp[TILE];   // pred_j
    __shared__ float st[TILE];   // target_j
    __shared__ float sf[TILE];   // flag_j

    const int ti = blockIdx.x;   // i-tile
    const int tj = blockIdx.y;   // j-tile
    const int bid = tj * NT + ti;
    const int tid = threadIdx.x;

    float sum = 0.0f;
    unsigned int cnt = 0;

    if (tj >= ti) {              // block-uniform condition -> barriers are safe
        const int ct = *colT;    // 0
        const int cf = *colF;    // 1

        const int j = tj * TILE + tid;
        sp[tid] = pred[j];
        st[tid] = gt[j * 2 + ct];
        sf[tid] = (gt[j * 2 + cf] == 1.0f) ? 1.0f : 0.0f;
        __syncthreads();

        const int i = ti * TILE + tid;
        const float pi = pred[i];
        const float tv = gt[i * 2 + ct];
        const bool  fi = (gt[i * 2 + cf] == 1.0f);

        if (fi) {
            if (ti == tj) {
                // diagonal tile: only j > i within the tile
                for (int jj = tid + 1; jj < TILE; ++jj) {
                    if (sf[jj] != 0.0f) {
                        float v = (pi - sp[jj]) * (tv - st[jj]) * 0.01f;
                        sum += fmaxf(v, 0.0f);
                        cnt++;
                    }
                }
            } else {
                #pragma unroll 8
                for (int jj = 0; jj < TILE; ++jj) {
                    if (sf[jj] != 0.0f) {   // wave-uniform branch (same jj all lanes)
                        float v = (pi - sp[jj]) * (tv - st[jj]) * 0.01f;
                        sum += fmaxf(v, 0.0f);
                        cnt++;
                    }
                }
            }
        }
    }

    // Block reduction: wave shuffle then cross-wave via LDS.
    for (int off = 32; off > 0; off >>= 1) {
        sum += __shfl_down(sum, off, 64);
        cnt += __shfl_down(cnt, off, 64);
    }
    __shared__ float        wsum[4];
    __shared__ unsigned int wcnt[4];
    const int wid  = tid >> 6;
    const int lane = tid & 63;
    __syncthreads();   // protect reuse after staging barrier pattern
    if (lane == 0) { wsum[wid] = sum; wcnt[wid] = cnt; }
    __syncthreads();
    if (tid == 0) {
        ws_sum[bid] = wsum[0] + wsum[1] + wsum[2] + wsum[3];
        ws_cnt[bid] = wcnt[0] + wcnt[1] + wcnt[2] + wcnt[3];
    }
}

// Stage 2: reduce all NT*NT partials (lower-triangle blocks wrote zeros).
__global__ __launch_bounds__(256) void finalize(
    const float* __restrict__ ws_sum,
    const unsigned int* __restrict__ ws_cnt,
    float* __restrict__ out)
{
    const int tid = threadIdx.x;
    double s = 0.0;
    unsigned long long c = 0;
    for (int i = tid; i < NT * NT; i += 256) {
        s += (double)ws_sum[i];
        c += (unsigned long long)ws_cnt[i];
    }
    for (int off = 32; off > 0; off >>= 1) {
        s += __shfl_down(s, off, 64);
        c += __shfl_down(c, off, 64);
    }
    __shared__ double             sd[4];
    __shared__ unsigned long long cd[4];
    const int wid  = tid >> 6;
    const int lane = tid & 63;
    if (lane == 0) { sd[wid] = s; cd[wid] = c; }
    __syncthreads();
    if (tid == 0) {
        double S = sd[0] + sd[1] + sd[2] + sd[3];
        double C = (double)(cd[0] + cd[1] + cd[2] + cd[3]);
        out[0] = (float)(S / C);
    }
}

extern "C" void kernel_launch(void* const* d_in, const int* in_sizes, int n_in,
                              void* d_out, int out_size, void* d_ws, size_t ws_size,
                              hipStream_t stream) {
    const float* pred = (const float*)d_in[0];
    const float* gt   = (const float*)d_in[1];
    const int*   colT = (const int*)d_in[2];
    const int*   colF = (const int*)d_in[3];

    float*        ws_sum = (float*)d_ws;
    unsigned int* ws_cnt = (unsigned int*)((char*)d_ws + NT * NT * sizeof(float));

    dim3 grid(NT, NT);
    pair_partial<<<grid, 256, 0, stream>>>(pred, gt, colT, colF, ws_sum, ws_cnt);
    finalize<<<1, 256, 0, stream>>>(ws_sum, ws_cnt, (float*)d_out);
}

// Round 2
// 18.220 us; speedup vs baseline: 1.9910x; 1.9910x over previous
//
#include <hip/hip_runtime.h>

#define NELEM 8192
#define JTILE 256
#define NJT   (NELEM / JTILE)   // 32 j-tiles
#define IBLK  512               // i-range per block (2 i's per thread)
#define NIB   (NELEM / IBLK)    // 16 i-blocks
#define NBLOCKS (NIB * NJT)     // 512 partials

// Full ordered-pair sum: S_full = sum_{i,j} fi*fj*max((pi-pj)(ti-tj)/100, 0)
//                              = 2 * sum_{i<j} (diagonal contributes 0).
// Unflagged j is masked by staging (p,t) = (-1e30, +1e30):
//   dp = pi+1e30 (finite>0), dt = ti*0.01-1e30 (finite<0), dp*dt -> -inf,
//   fmaxf(-inf, 0) = 0. IEEE-safe, no NaN, no branch.
// Unflagged i is masked by one multiply per accumulator outside the loop.
__global__ __launch_bounds__(256) void pair_kernel(
    const float* __restrict__ pred,
    const float* __restrict__ gt,
    const int* __restrict__ colT,
    const int* __restrict__ colF,
    float* __restrict__ ws_sum)
{
    __shared__ float2 sj[JTILE];

    const int tid = threadIdx.x;
    const int ib  = blockIdx.x;   // 0..NIB-1
    const int tj  = blockIdx.y;   // 0..NJT-1
    const int ct  = colT[0];      // 0
    const int cf  = colF[0];      // 1

    // Stage this block's j-tile: masked (p, 0.01*t) pairs.
    {
        const int j = tj * JTILE + tid;
        const float2 g = ((const float2*)gt)[j];
        const float tv = (ct == 0) ? g.x : g.y;
        const float fv = (cf == 0) ? g.x : g.y;
        const float pj = pred[j];
        const bool  fl = (fv == 1.0f);
        float2 e;
        e.x = fl ? pj          : -1e30f;
        e.y = fl ? tv * 0.01f  :  1e30f;
        sj[tid] = e;
    }
    __syncthreads();

    // Two register-blocked i's per thread.
    const int i0 = ib * IBLK + tid;
    const int i1 = i0 + 256;
    const float2 g0 = ((const float2*)gt)[i0];
    const float2 g1 = ((const float2*)gt)[i1];
    const float p0 = pred[i0];
    const float p1 = pred[i1];
    const float t0 = ((ct == 0) ? g0.x : g0.y) * 0.01f;
    const float t1 = ((ct == 0) ? g1.x : g1.y) * 0.01f;
    const float f0 = (((cf == 0) ? g0.x : g0.y) == 1.0f) ? 1.0f : 0.0f;
    const float f1 = (((cf == 0) ? g1.x : g1.y) == 1.0f) ? 1.0f : 0.0f;

    float a0 = 0.0f, a1 = 0.0f;
    #pragma unroll 8
    for (int jj = 0; jj < JTILE; ++jj) {
        const float2 v = sj[jj];                      // ds_read_b64 broadcast
        a0 += fmaxf((p0 - v.x) * (t0 - v.y), 0.0f);   // 5 VALU per pair
        a1 += fmaxf((p1 - v.x) * (t1 - v.y), 0.0f);
    }
    float s = a0 * f0 + a1 * f1;

    // Block reduction (fixed tree -> deterministic).
    for (int off = 32; off > 0; off >>= 1) s += __shfl_down(s, off, 64);
    __shared__ float wsum[4];
    if ((tid & 63) == 0) wsum[tid >> 6] = s;
    __syncthreads();
    if (tid == 0) ws_sum[tj * NIB + ib] = wsum[0] + wsum[1] + wsum[2] + wsum[3];
}

// Reduce the 512 partials (double) and compute M = #flagged; out = S / (M*(M-1)).
__global__ __launch_bounds__(256) void finalize(
    const float* __restrict__ ws_sum,
    const float* __restrict__ gt,
    const int* __restrict__ colF,
    float* __restrict__ out)
{
    const int tid = threadIdx.x;
    const int cf  = colF[0];

    double s = 0.0;
    for (int i = tid; i < NBLOCKS; i += 256) s += (double)ws_sum[i];

    int m = 0;
    for (int i = tid; i < NELEM; i += 256) {
        const float2 g = ((const float2*)gt)[i];
        const float fv = (cf == 0) ? g.x : g.y;
        m += (fv == 1.0f) ? 1 : 0;
    }

    for (int off = 32; off > 0; off >>= 1) {
        s += __shfl_down(s, off, 64);
        m += __shfl_down(m, off, 64);
    }
    __shared__ double sd[4];
    __shared__ int    md[4];
    if ((tid & 63) == 0) { sd[tid >> 6] = s; md[tid >> 6] = m; }
    __syncthreads();
    if (tid == 0) {
        const double S = sd[0] + sd[1] + sd[2] + sd[3];
        const double M = (double)(md[0] + md[1] + md[2] + md[3]);
        out[0] = (float)(S / (M * (M - 1.0)));   // = (S/2) / C(M,2)
    }
}

extern "C" void kernel_launch(void* const* d_in, const int* in_sizes, int n_in,
                              void* d_out, int out_size, void* d_ws, size_t ws_size,
                              hipStream_t stream) {
    const float* pred = (const float*)d_in[0];
    const float* gt   = (const float*)d_in[1];
    const int*   colT = (const int*)d_in[2];
    const int*   colF = (const int*)d_in[3];

    float* ws_sum = (float*)d_ws;   // NBLOCKS floats

    dim3 grid(NIB, NJT);
    pair_kernel<<<grid, 256, 0, stream>>>(pred, gt, colT, colF, ws_sum);
    finalize<<<1, 256, 0, stream>>>(ws_sum, gt, colF, (float*)d_out);
}

// Round 3
// 16.610 us; speedup vs baseline: 2.1840x; 1.0970x over previous
//
#include <hip/hip_runtime.h>

#define NELEM 8192
#define JTILE 32
#define NJT   (NELEM / JTILE)     // 256 j-tiles
#define IPT   16                  // i's per thread
#define IBLK  (256 * IPT)         // 4096 i's per block
#define NIB   (NELEM / IBLK)      // 2 i-blocks
#define NBLK  (NIB * NJT)         // 512 partial sums

// Loss = [sum_{i<j} fi fj max((pi-pj)(ti-tj)/100, 0)] / C(M,2),  M = #flagged.
// With t' = 0.01*t and max(x,0) = (x+|x|)/2 over the full ordered square:
//   A = sum_{i,j} fi fj (pi-pj)(t'i-t'j) = 2[M*T - P*Q]        (closed form)
//       where T = sum f p t', P = sum f p, Q = sum f t'
//   B = sum_{i,j} fi fj |pi-pj||t'i-t'j|                        (pair kernel)
//   Loss = (A + B) / (2 M (M-1))
// B via staged arrays (p~j, t~j) = fj ? (pj, t'j) : (0,0):
//   B = B_raw - (N - M) * D,   D = sum_i fi |pi t'i|
// Inner op: acc = fma(|pi - p~j|, |t'i - t~j|, acc)  -> 3 VALU/pair
// (abs folds into VOP3 source modifiers; i-side flag applied once per acc).
__global__ __launch_bounds__(256) void pair_kernel(
    const float* __restrict__ pred,
    const float* __restrict__ gt,
    const int* __restrict__ colT,
    const int* __restrict__ colF,
    float* __restrict__ ws)   // [NBLK] B_raw partials, then [NIB*5] scalar sums
{
    __shared__ float2 sj[JTILE];
    const int tid = threadIdx.x;
    const int ib  = blockIdx.x;   // 0..NIB-1
    const int tj  = blockIdx.y;   // 0..NJT-1
    const int ct  = colT[0];      // 0
    const int cf  = colF[0];      // 1

    if (tid < JTILE) {
        const int j = tj * JTILE + tid;
        const float2 g = ((const float2*)gt)[j];
        const float tv = (ct == 0) ? g.x : g.y;
        const float fv = (cf == 0) ? g.x : g.y;
        const float pj = pred[j];
        const bool  fl = (fv == 1.0f);
        sj[tid] = make_float2(fl ? pj : 0.0f, fl ? tv * 0.01f : 0.0f);
    }
    __syncthreads();

    float p[IPT], t[IPT], f[IPT], acc[IPT];
    #pragma unroll
    for (int k = 0; k < IPT; ++k) {
        const int i = ib * IBLK + k * 256 + tid;
        const float2 g = ((const float2*)gt)[i];
        p[k] = pred[i];
        t[k] = ((ct == 0) ? g.x : g.y) * 0.01f;
        f[k] = (((cf == 0) ? g.x : g.y) == 1.0f) ? 1.0f : 0.0f;
        acc[k] = 0.0f;
    }

    #pragma unroll 4
    for (int jj = 0; jj < JTILE; ++jj) {
        const float2 v = sj[jj];              // ds_read_b64 broadcast (uniform)
        #pragma unroll
        for (int k = 0; k < IPT; ++k)
            acc[k] = fmaf(fabsf(p[k] - v.x), fabsf(t[k] - v.y), acc[k]);
    }

    float s = 0.0f;
    #pragma unroll
    for (int k = 0; k < IPT; ++k) s = fmaf(f[k], acc[k], s);

    for (int off = 32; off > 0; off >>= 1) s += __shfl_down(s, off, 64);
    __shared__ float wsum[4];
    if ((tid & 63) == 0) wsum[tid >> 6] = s;
    __syncthreads();
    if (tid == 0) ws[tj * NIB + ib] = wsum[0] + wsum[1] + wsum[2] + wsum[3];

    // O(N) scalar sums, piggybacked on the tj==0 blocks (i-data already live).
    if (tj == 0) {   // block-uniform -> barrier safe
        float c = 0, sp = 0, st = 0, spt = 0, sab = 0;
        #pragma unroll
        for (int k = 0; k < IPT; ++k) {
            const float pt = p[k] * t[k];
            c   += f[k];
            sp   = fmaf(f[k], p[k], sp);
            st   = fmaf(f[k], t[k], st);
            spt  = fmaf(f[k], pt, spt);
            sab  = fmaf(f[k], fabsf(pt), sab);
        }
        for (int off = 32; off > 0; off >>= 1) {
            c   += __shfl_down(c,   off, 64);
            sp  += __shfl_down(sp,  off, 64);
            st  += __shfl_down(st,  off, 64);
            spt += __shfl_down(spt, off, 64);
            sab += __shfl_down(sab, off, 64);
        }
        __shared__ float s5[4][5];
        const int wid = tid >> 6;
        if ((tid & 63) == 0) {
            s5[wid][0] = c;  s5[wid][1] = sp;  s5[wid][2] = st;
            s5[wid][3] = spt; s5[wid][4] = sab;
        }
        __syncthreads();
        if (tid == 0) {
            float* o = ws + NBLK + ib * 5;
            #pragma unroll
            for (int m = 0; m < 5; ++m)
                o[m] = s5[0][m] + s5[1][m] + s5[2][m] + s5[3][m];
        }
    }
}

__global__ __launch_bounds__(256) void finalize(
    const float* __restrict__ ws,
    float* __restrict__ out)
{
    const int tid = threadIdx.x;
    double s = 0.0;
    for (int i = tid; i < NBLK; i += 256) s += (double)ws[i];
    for (int off = 32; off > 0; off >>= 1) s += __shfl_down(s, off, 64);
    __shared__ double sd[4];
    if ((tid & 63) == 0) sd[tid >> 6] = s;
    __syncthreads();
    if (tid == 0) {
        const double Braw = sd[0] + sd[1] + sd[2] + sd[3];
        double M = 0, P = 0, Q = 0, T = 0, D = 0;
        for (int ib = 0; ib < NIB; ++ib) {
            const float* o = ws + NBLK + ib * 5;
            M += (double)o[0]; P += (double)o[1]; Q += (double)o[2];
            T += (double)o[3]; D += (double)o[4];
        }
        const double A = 2.0 * (M * T - P * Q);
        const double B = Braw - ((double)NELEM - M) * D;
        out[0] = (float)((A + B) / (2.0 * M * (M - 1.0)));
    }
}

extern "C" void kernel_launch(void* const* d_in, const int* in_sizes, int n_in,
                              void* d_out, int out_size, void* d_ws, size_t ws_size,
                              hipStream_t stream) {
    const float* pred = (const float*)d_in[0];
    const float* gt   = (const float*)d_in[1];
    const int*   colT = (const int*)d_in[2];
    const int*   colF = (const int*)d_in[3];

    float* ws = (float*)d_ws;   // NBLK + NIB*5 floats

    dim3 grid(NIB, NJT);
    pair_kernel<<<grid, 256, 0, stream>>>(pred, gt, colT, colF, ws);
    finalize<<<1, 256, 0, stream>>>(ws, (float*)d_out);
}